// Round 1
// baseline (2958.279 us; speedup 1.0000x reference)
//
#include <hip/hip_runtime.h>

#define L_  2048
#define D_  512
#define H_  8
#define DH_ 64
#define BH_ 16
#define PE_ 2097152ull   // B*L*D elements in one projection array

// ============================================================
// QKV projection: C = X @ W^T + b  -> head-split layout
// X: (4096,512), W: (512,512) row-major (n,k)
// out[((b*H + h)*L + i)*64 + dh],  n = h*64+dh
// z = 0..5 : (wave_real,Wq) (wave_imag,Wq) (wr,Wk) (wi,Wk) (wr,Wv) (wi,Wv)
// ============================================================
__global__ __launch_bounds__(256)
void proj_qkv_kernel(const float* __restrict__ wave_real,
                     const float* __restrict__ wave_imag,
                     const float* __restrict__ Wq, const float* __restrict__ bq,
                     const float* __restrict__ Wk, const float* __restrict__ bk,
                     const float* __restrict__ Wv, const float* __restrict__ bv,
                     float* __restrict__ ws)
{
    const int z = blockIdx.z;
    const float* X = (z & 1) ? wave_imag : wave_real;
    const float* W; const float* bias;
    if ((z >> 1) == 0)      { W = Wq; bias = bq; }
    else if ((z >> 1) == 1) { W = Wk; bias = bk; }
    else                    { W = Wv; bias = bv; }
    float* outp = ws + (size_t)z * PE_;

    const int m0 = blockIdx.x * 64;
    const int h  = blockIdx.y;        // one head per 64-wide n-tile
    const int n0 = h * 64;

    __shared__ float Xs[16][65];
    __shared__ float Wt[16][65];

    const int tid  = threadIdx.x;
    const int tx   = tid & 15, ty = tid >> 4;
    const int lrow = tid >> 2;          // 0..63
    const int kq   = (tid & 3) * 4;     // 0,4,8,12

    float acc[4][4] = {};

    for (int k0 = 0; k0 < 512; k0 += 16) {
        __syncthreads();
        float4 xv = *(const float4*)&X[(size_t)(m0 + lrow) * 512 + k0 + kq];
        float4 wv = *(const float4*)&W[(size_t)(n0 + lrow) * 512 + k0 + kq];
        Xs[kq+0][lrow] = xv.x; Xs[kq+1][lrow] = xv.y; Xs[kq+2][lrow] = xv.z; Xs[kq+3][lrow] = xv.w;
        Wt[kq+0][lrow] = wv.x; Wt[kq+1][lrow] = wv.y; Wt[kq+2][lrow] = wv.z; Wt[kq+3][lrow] = wv.w;
        __syncthreads();
        #pragma unroll
        for (int k = 0; k < 16; ++k) {
            float a[4], bb[4];
            #pragma unroll
            for (int r = 0; r < 4; ++r) a[r] = Xs[k][ty*4 + r];
            #pragma unroll
            for (int c = 0; c < 4; ++c) bb[c] = Wt[k][tx*4 + c];
            #pragma unroll
            for (int r = 0; r < 4; ++r)
                #pragma unroll
                for (int c = 0; c < 4; ++c) acc[r][c] += a[r] * bb[c];
        }
    }

    const float4 b4 = *(const float4*)&bias[n0 + tx*4];
    #pragma unroll
    for (int r = 0; r < 4; ++r) {
        const int t  = m0 + ty*4 + r;
        const int b_ = t >> 11, i = t & 2047;
        float4 v;
        v.x = acc[r][0] + b4.x;
        v.y = acc[r][1] + b4.y;
        v.z = acc[r][2] + b4.z;
        v.w = acc[r][3] + b4.w;
        *(float4*)&outp[(((size_t)b_*H_ + h)*L_ + i)*DH_ + tx*4] = v;
    }
}

// ============================================================
// Fused attention: per (b*H+h, 64-row Q tile)
// sweep1: exact row max of scores (recompute QK)
// sweep2: recompute QK, write e=exp(s-m) to attn output (unnormalized),
//         build ac/as in LDS, stage V, accumulate PV in registers.
// End: fold 1/l into O write, store l for scale_attn.
// ============================================================
__global__ __launch_bounds__(256)
void attn_pv_kernel(const float* __restrict__ ws,
                    float* __restrict__ attnbuf,
                    float* __restrict__ o_r, float* __restrict__ o_i,
                    float* __restrict__ l_out)
{
    const int it = blockIdx.x;          // 0..31
    const int bh = blockIdx.y;          // 0..15
    const int i0 = it * 64;
    const size_t hb = (size_t)bh * L_ * DH_;
    const float* Qr = ws + 0*PE_ + hb;
    const float* Qi = ws + 1*PE_ + hb;
    const float* Kr = ws + 2*PE_ + hb;
    const float* Ki = ws + 3*PE_ + hb;
    const float* Vr = ws + 4*PE_ + hb;
    const float* Vi = ws + 5*PE_ + hb;

    __shared__ float Qsr[64][66], Qsi[64][66];
    __shared__ float Ksr[64][66], Ksi[64][66];   // K during GEMM, V during PV
    __shared__ float Sa[64][65],  Sb[64][65];    // ac, as
    __shared__ float ls[64];

    const int tid  = threadIdx.x;
    const int tx   = tid & 15, ty = tid >> 4;
    const int lrow = tid >> 2;          // 0..63
    const int q4   = (tid & 3) * 16;    // 16 dh per thread per row

    // ---- stage Q tile once ----
    #pragma unroll
    for (int u = 0; u < 4; ++u) {
        float4 a = *(const float4*)&Qr[(size_t)(i0 + lrow)*DH_ + q4 + u*4];
        float4 b = *(const float4*)&Qi[(size_t)(i0 + lrow)*DH_ + q4 + u*4];
        Qsr[lrow][q4+u*4+0] = a.x; Qsr[lrow][q4+u*4+1] = a.y;
        Qsr[lrow][q4+u*4+2] = a.z; Qsr[lrow][q4+u*4+3] = a.w;
        Qsi[lrow][q4+u*4+0] = b.x; Qsi[lrow][q4+u*4+1] = b.y;
        Qsi[lrow][q4+u*4+2] = b.z; Qsi[lrow][q4+u*4+3] = b.w;
    }

    // ---------------- sweep 1: row max ----------------
    float mx[4] = {0.f, 0.f, 0.f, 0.f};   // scores >= 0
    for (int jt = 0; jt < 32; ++jt) {
        __syncthreads();
        #pragma unroll
        for (int u = 0; u < 4; ++u) {
            float4 a = *(const float4*)&Kr[(size_t)(jt*64 + lrow)*DH_ + q4 + u*4];
            float4 b = *(const float4*)&Ki[(size_t)(jt*64 + lrow)*DH_ + q4 + u*4];
            Ksr[lrow][q4+u*4+0] = a.x; Ksr[lrow][q4+u*4+1] = a.y;
            Ksr[lrow][q4+u*4+2] = a.z; Ksr[lrow][q4+u*4+3] = a.w;
            Ksi[lrow][q4+u*4+0] = b.x; Ksi[lrow][q4+u*4+1] = b.y;
            Ksi[lrow][q4+u*4+2] = b.z; Ksi[lrow][q4+u*4+3] = b.w;
        }
        __syncthreads();
        float ir[4][4] = {}, ii[4][4] = {};
        #pragma unroll 4
        for (int k = 0; k < 64; ++k) {
            float ar[4], ai[4], br[4], bi[4];
            #pragma unroll
            for (int r = 0; r < 4; ++r) { ar[r] = Qsr[ty*4+r][k]; ai[r] = Qsi[ty*4+r][k]; }
            #pragma unroll
            for (int c = 0; c < 4; ++c) { br[c] = Ksr[tx*4+c][k]; bi[c] = Ksi[tx*4+c][k]; }
            #pragma unroll
            for (int r = 0; r < 4; ++r)
                #pragma unroll
                for (int c = 0; c < 4; ++c) {
                    ir[r][c] += ar[r]*br[c] + ai[r]*bi[c];
                    ii[r][c] += ar[r]*bi[c] - ai[r]*br[c];
                }
        }
        #pragma unroll
        for (int r = 0; r < 4; ++r)
            #pragma unroll
            for (int c = 0; c < 4; ++c) {
                float q = ir[r][c]*ir[r][c] + ii[r][c]*ii[r][c];
                mx[r] = fmaxf(mx[r], q * 0.125f);
            }
    }
    #pragma unroll
    for (int off = 1; off < 16; off <<= 1) {
        #pragma unroll
        for (int r = 0; r < 4; ++r) mx[r] = fmaxf(mx[r], __shfl_xor(mx[r], off));
    }

    // ---------------- sweep 2 ----------------
    float o_rr[4][4] = {}, o_ri[4][4] = {};
    float lp[4] = {0.f, 0.f, 0.f, 0.f};
    for (int jt = 0; jt < 32; ++jt) {
        const int j0 = jt * 64;
        __syncthreads();   // prior PV done -> safe to overwrite Ks / Sa
        #pragma unroll
        for (int u = 0; u < 4; ++u) {
            float4 a = *(const float4*)&Kr[(size_t)(j0 + lrow)*DH_ + q4 + u*4];
            float4 b = *(const float4*)&Ki[(size_t)(j0 + lrow)*DH_ + q4 + u*4];
            Ksr[lrow][q4+u*4+0] = a.x; Ksr[lrow][q4+u*4+1] = a.y;
            Ksr[lrow][q4+u*4+2] = a.z; Ksr[lrow][q4+u*4+3] = a.w;
            Ksi[lrow][q4+u*4+0] = b.x; Ksi[lrow][q4+u*4+1] = b.y;
            Ksi[lrow][q4+u*4+2] = b.z; Ksi[lrow][q4+u*4+3] = b.w;
        }
        __syncthreads();
        float ir[4][4] = {}, ii[4][4] = {};
        #pragma unroll 4
        for (int k = 0; k < 64; ++k) {
            float ar[4], ai[4], br[4], bi[4];
            #pragma unroll
            for (int r = 0; r < 4; ++r) { ar[r] = Qsr[ty*4+r][k]; ai[r] = Qsi[ty*4+r][k]; }
            #pragma unroll
            for (int c = 0; c < 4; ++c) { br[c] = Ksr[tx*4+c][k]; bi[c] = Ksi[tx*4+c][k]; }
            #pragma unroll
            for (int r = 0; r < 4; ++r)
                #pragma unroll
                for (int c = 0; c < 4; ++c) {
                    ir[r][c] += ar[r]*br[c] + ai[r]*bi[c];
                    ii[r][c] += ar[r]*bi[c] - ai[r]*br[c];
                }
        }
        __syncthreads();   // all K reads done -> overwrite with V
        #pragma unroll
        for (int u = 0; u < 4; ++u) {
            float4 a = *(const float4*)&Vr[(size_t)(j0 + lrow)*DH_ + q4 + u*4];
            float4 b = *(const float4*)&Vi[(size_t)(j0 + lrow)*DH_ + q4 + u*4];
            Ksr[lrow][q4+u*4+0] = a.x; Ksr[lrow][q4+u*4+1] = a.y;
            Ksr[lrow][q4+u*4+2] = a.z; Ksr[lrow][q4+u*4+3] = a.w;
            Ksi[lrow][q4+u*4+0] = b.x; Ksi[lrow][q4+u*4+1] = b.y;
            Ksi[lrow][q4+u*4+2] = b.z; Ksi[lrow][q4+u*4+3] = b.w;
        }
        // per-element: e = exp(s-m); cos/sin from ir,ii (no atan2)
        #pragma unroll
        for (int r = 0; r < 4; ++r) {
            float ev[4];
            #pragma unroll
            for (int c = 0; c < 4; ++c) {
                float xr = ir[r][c], xi = ii[r][c];
                float q  = xr*xr + xi*xi;
                float e  = expf(q * 0.125f - mx[r]);
                float cc, ss;
                if (q > 0.f) { float inv = rsqrtf(q); cc = xr * inv; ss = xi * inv; }
                else         { cc = 1.f; ss = 0.f; }   // atan2(0,0)=0
                Sa[ty*4+r][tx*4+c] = e * cc;
                Sb[ty*4+r][tx*4+c] = e * ss;
                lp[r] += e;
                ev[c] = e;
            }
            *(float4*)&attnbuf[((size_t)bh*L_ + i0 + ty*4 + r)*L_ + j0 + tx*4] =
                make_float4(ev[0], ev[1], ev[2], ev[3]);
        }
        __syncthreads();   // V + Sa/Sb visible
        // PV: o += ac*V_r - as*V_i ; o_i += as*V_r + ac*V_i
        #pragma unroll 2
        for (int j = 0; j < 64; ++j) {
            float vr[4], vi[4];
            #pragma unroll
            for (int c = 0; c < 4; ++c) { vr[c] = Ksr[j][tx*4+c]; vi[c] = Ksi[j][tx*4+c]; }
            #pragma unroll
            for (int rr = 0; rr < 4; ++rr) {
                float a = Sa[ty + 16*rr][j], b = Sb[ty + 16*rr][j];
                #pragma unroll
                for (int c = 0; c < 4; ++c) {
                    o_rr[rr][c] += a * vr[c] - b * vi[c];
                    o_ri[rr][c] += b * vr[c] + a * vi[c];
                }
            }
        }
    }

    // row sums l
    #pragma unroll
    for (int off = 1; off < 16; off <<= 1) {
        #pragma unroll
        for (int r = 0; r < 4; ++r) lp[r] += __shfl_xor(lp[r], off);
    }
    if (tx == 0) {
        #pragma unroll
        for (int r = 0; r < 4; ++r) {
            ls[ty*4 + r] = lp[r];
            l_out[(size_t)bh*L_ + i0 + ty*4 + r] = lp[r];
        }
    }
    __syncthreads();

    const int b_ = bh >> 3, h = bh & 7;
    #pragma unroll
    for (int rr = 0; rr < 4; ++rr) {
        const int i = i0 + ty + 16*rr;
        const float invl = 1.f / ls[ty + 16*rr];
        const size_t base = ((size_t)b_*L_ + i)*D_ + h*DH_ + tx*4;
        float4 vR = make_float4(o_rr[rr][0]*invl, o_rr[rr][1]*invl, o_rr[rr][2]*invl, o_rr[rr][3]*invl);
        float4 vI = make_float4(o_ri[rr][0]*invl, o_ri[rr][1]*invl, o_ri[rr][2]*invl, o_ri[rr][3]*invl);
        *(float4*)&o_r[base] = vR;
        *(float4*)&o_i[base] = vI;
    }
}

// ============================================================
// attention *= 1/l[row]  (in place, 16.7M float4)
// ============================================================
__global__ __launch_bounds__(256)
void scale_attn_kernel(float* __restrict__ attnbuf, const float* __restrict__ l)
{
    const size_t idx = (size_t)blockIdx.x * 256 + threadIdx.x;  // float4 index
    const size_t row = idx >> 9;                                // L/4 = 512 float4 per row
    const float inv = 1.f / l[row];
    float4* p = (float4*)attnbuf + idx;
    float4 v = *p;
    v.x *= inv; v.y *= inv; v.z *= inv; v.w *= inv;
    *p = v;
}

// ============================================================
// output projection: out = X @ Wo^T + bo, row-major (B*L, D)
// z=0: o_real -> d_out[0..]; z=1: o_imag -> d_out[PE_..]
// ============================================================
__global__ __launch_bounds__(256)
void out_proj_kernel(const float* __restrict__ o_r, const float* __restrict__ o_i,
                     const float* __restrict__ Wo, const float* __restrict__ bo,
                     float* __restrict__ out)
{
    const int z = blockIdx.z;
    const float* X = z ? o_i : o_r;
    float* outp = out + (size_t)z * PE_;

    const int m0 = blockIdx.x * 64;
    const int n0 = blockIdx.y * 64;

    __shared__ float Xs[16][65];
    __shared__ float Wt[16][65];

    const int tid  = threadIdx.x;
    const int tx   = tid & 15, ty = tid >> 4;
    const int lrow = tid >> 2;
    const int kq   = (tid & 3) * 4;

    float acc[4][4] = {};

    for (int k0 = 0; k0 < 512; k0 += 16) {
        __syncthreads();
        float4 xv = *(const float4*)&X [(size_t)(m0 + lrow) * 512 + k0 + kq];
        float4 wv = *(const float4*)&Wo[(size_t)(n0 + lrow) * 512 + k0 + kq];
        Xs[kq+0][lrow] = xv.x; Xs[kq+1][lrow] = xv.y; Xs[kq+2][lrow] = xv.z; Xs[kq+3][lrow] = xv.w;
        Wt[kq+0][lrow] = wv.x; Wt[kq+1][lrow] = wv.y; Wt[kq+2][lrow] = wv.z; Wt[kq+3][lrow] = wv.w;
        __syncthreads();
        #pragma unroll
        for (int k = 0; k < 16; ++k) {
            float a[4], bb[4];
            #pragma unroll
            for (int r = 0; r < 4; ++r) a[r] = Xs[k][ty*4 + r];
            #pragma unroll
            for (int c = 0; c < 4; ++c) bb[c] = Wt[k][tx*4 + c];
            #pragma unroll
            for (int r = 0; r < 4; ++r)
                #pragma unroll
                for (int c = 0; c < 4; ++c) acc[r][c] += a[r] * bb[c];
        }
    }

    const float4 b4 = *(const float4*)&bo[n0 + tx*4];
    #pragma unroll
    for (int r = 0; r < 4; ++r) {
        const int t = m0 + ty*4 + r;
        float4 v;
        v.x = acc[r][0] + b4.x;
        v.y = acc[r][1] + b4.y;
        v.z = acc[r][2] + b4.z;
        v.w = acc[r][3] + b4.w;
        *(float4*)&outp[(size_t)t*512 + n0 + tx*4] = v;
    }
}

// ============================================================
extern "C" void kernel_launch(void* const* d_in, const int* in_sizes, int n_in,
                              void* d_out, int out_size, void* d_ws, size_t ws_size,
                              hipStream_t stream)
{
    const float* wave_real = (const float*)d_in[0];
    const float* wave_imag = (const float*)d_in[1];
    const float* Wq = (const float*)d_in[2]; const float* bq = (const float*)d_in[3];
    const float* Wk = (const float*)d_in[4]; const float* bk = (const float*)d_in[5];
    const float* Wv = (const float*)d_in[6]; const float* bv = (const float*)d_in[7];
    const float* Wo = (const float*)d_in[8]; const float* bo = (const float*)d_in[9];
    float* out = (float*)d_out;
    float* ws  = (float*)d_ws;

    // ws layout (floats): [0..6P): Qr,Qi,Kr,Ki,Vr,Vi  [6P..7P): o_pre_r
    // [7P..8P): o_pre_i  [8P..8P+32768): l      total 67.2 MB
    float* attnbuf = out + 2*PE_;          // (B*H, L, L) region of d_out
    float* o_r = ws + 6*PE_;
    float* o_i = ws + 7*PE_;
    float* l   = ws + 8*PE_;

    proj_qkv_kernel <<<dim3(64, 8, 6), dim3(256), 0, stream>>>(wave_real, wave_imag,
                                                               Wq, bq, Wk, bk, Wv, bv, ws);
    attn_pv_kernel  <<<dim3(32, 16),   dim3(256), 0, stream>>>(ws, attnbuf, o_r, o_i, l);
    scale_attn_kernel<<<dim3(65536),   dim3(256), 0, stream>>>(attnbuf, l);
    out_proj_kernel <<<dim3(64, 8, 2), dim3(256), 0, stream>>>(o_r, o_i, Wo, bo, out);
}

// Round 2
// 653.886 us; speedup vs baseline: 4.5241x; 4.5241x over previous
//
#include <hip/hip_runtime.h>

typedef unsigned short u16;
typedef unsigned int   u32;
typedef __attribute__((ext_vector_type(4)))  u16   us4;
typedef __attribute__((ext_vector_type(8)))  u16   us8;
typedef __attribute__((ext_vector_type(8)))  short s8v;
typedef __attribute__((ext_vector_type(16))) float f32x16;

#define L_   2048
#define D_   512
#define H_   8
#define PE_  2097152ull      // B*L*D elements of one fp32 projection array

// ws layout (bytes):
//  [0 .. 32MB)   : 8 bf16 mats (QRH,QRL,QIH,QIL,KRH,KRL,KIH,KIL), each [bh][i][64]
//  [32 .. 40MB)  : 2 bf16 mats VTR,VTI, each [bh][dh][2048]  (V transposed)
//  [40 .. 48MB)  : o_pre_real fp32 [b][i][512]
//  [48 .. 56MB)  : o_pre_imag fp32
//  [56MB ..]     : l (32768 fp32)
#define MATE   2097152ull    // u16 elems per mat
#define BHE    131072u       // u16 elems per (bh) slice of a mat (2048*64)
#define VT_OFF 33554432ull
#define OR_OFF 41943040ull
#define OI_OFF 50331648ull
#define LV_OFF 58720256ull

#define MFMA32(a,b,c) __builtin_amdgcn_mfma_f32_32x32x16_bf16(a,b,c,0,0,0)
#define ROWOF(r,hi) (((r)&3) + 8*((r)>>2) + 4*(hi))

__device__ __forceinline__ u16 f2bf(float x){
    u32 u = __float_as_uint(x);
    u += 0x7FFFu + ((u>>16)&1u);
    return (u16)(u>>16);
}
__device__ __forceinline__ float bf2f(u16 h){ return __uint_as_float(((u32)h)<<16); }

// ============================================================
// QKV projection (fp32 VALU GEMM, unchanged core).
// z = 0..5 : (wr,Wq)(wi,Wq)(wr,Wk)(wi,Wk)(wr,Wv)(wi,Wv)
// z<4  -> split bf16 hi/lo mats [bh][i][64]
// z>=4 -> bf16 transposed V [bh][dh][2048]
// ============================================================
__global__ __launch_bounds__(256)
void proj_qkv_kernel(const float* __restrict__ wave_real,
                     const float* __restrict__ wave_imag,
                     const float* __restrict__ Wq, const float* __restrict__ bq,
                     const float* __restrict__ Wk, const float* __restrict__ bk,
                     const float* __restrict__ Wv, const float* __restrict__ bv,
                     unsigned char* __restrict__ wsb)
{
    const int z = blockIdx.z;
    const float* X = (z & 1) ? wave_imag : wave_real;
    const float* W; const float* bias;
    if ((z >> 1) == 0)      { W = Wq; bias = bq; }
    else if ((z >> 1) == 1) { W = Wk; bias = bk; }
    else                    { W = Wv; bias = bv; }

    const int m0 = blockIdx.x * 64;
    const int h  = blockIdx.y;
    const int n0 = h * 64;

    __shared__ float Xs[16][65];
    __shared__ float Wt[16][65];

    const int tid  = threadIdx.x;
    const int tx   = tid & 15, ty = tid >> 4;
    const int lrow = tid >> 2;
    const int kq   = (tid & 3) * 4;

    float acc[4][4] = {};

    for (int k0 = 0; k0 < 512; k0 += 16) {
        __syncthreads();
        float4 xv = *(const float4*)&X[(size_t)(m0 + lrow) * 512 + k0 + kq];
        float4 wv = *(const float4*)&W[(size_t)(n0 + lrow) * 512 + k0 + kq];
        Xs[kq+0][lrow] = xv.x; Xs[kq+1][lrow] = xv.y; Xs[kq+2][lrow] = xv.z; Xs[kq+3][lrow] = xv.w;
        Wt[kq+0][lrow] = wv.x; Wt[kq+1][lrow] = wv.y; Wt[kq+2][lrow] = wv.z; Wt[kq+3][lrow] = wv.w;
        __syncthreads();
        #pragma unroll
        for (int k = 0; k < 16; ++k) {
            float a[4], bb[4];
            #pragma unroll
            for (int r = 0; r < 4; ++r) a[r] = Xs[k][ty*4 + r];
            #pragma unroll
            for (int c = 0; c < 4; ++c) bb[c] = Wt[k][tx*4 + c];
            #pragma unroll
            for (int r = 0; r < 4; ++r)
                #pragma unroll
                for (int c = 0; c < 4; ++c) acc[r][c] += a[r] * bb[c];
        }
    }

    const float4 b4 = *(const float4*)&bias[n0 + tx*4];
    const float bb4[4] = { b4.x, b4.y, b4.z, b4.w };

    const int tbase = m0 + ty*4;
    const int b_ = tbase >> 11;
    const int i_ = tbase & 2047;        // rows i_ .. i_+3 (same batch, m0 % 64 == 0)
    const int bh = b_*H_ + h;

    if (z < 4) {
        u16* hg = (u16*)wsb + (size_t)(2*z)   * MATE + (size_t)bh * BHE;
        u16* lg = (u16*)wsb + (size_t)(2*z+1) * MATE + (size_t)bh * BHE;
        #pragma unroll
        for (int r = 0; r < 4; ++r) {
            us4 hv, lv;
            #pragma unroll
            for (int c = 0; c < 4; ++c) {
                float v = acc[r][c] + bb4[c];
                u16 hb = f2bf(v);
                hv[c] = hb;
                lv[c] = f2bf(v - bf2f(hb));
            }
            size_t idx = (size_t)(i_ + r)*64 + tx*4;
            *(us4*)(hg + idx) = hv;
            *(us4*)(lg + idx) = lv;
        }
    } else {
        u16* vg = (u16*)(wsb + VT_OFF) + (size_t)(z-4) * MATE + (size_t)bh * BHE;
        #pragma unroll
        for (int c = 0; c < 4; ++c) {
            us4 pv;
            #pragma unroll
            for (int r = 0; r < 4; ++r) pv[r] = f2bf(acc[r][c] + bb4[c]);
            *(us4*)(vg + (size_t)(tx*4 + c)*2048 + i_) = pv;   // [dh][i]
        }
    }
}

// ============================================================
// LDS staging helpers (XOR-swizzled, both sides: byte ^= (row&7)<<4)
// ============================================================
__device__ __forceinline__ void stage_qk(unsigned char* Lp, u32 matOff,
                                         const u16* __restrict__ g, int rowBase, int tid)
{
    const int ch = tid & 7;          // 16B chunk within 128B row
    const int r0 = tid >> 3;         // 0..31
    #pragma unroll
    for (int rr = 0; rr < 2; ++rr) {
        u32 row = rr*32 + r0;
        us8 v = ((const us8*)(g + (size_t)(rowBase + row)*64))[ch];
        *(us8*)(Lp + matOff + row*128u + (((u32)ch<<4) ^ ((row&7u)<<4))) = v;
    }
}
__device__ __forceinline__ void stage_vt(unsigned char* Lp, u32 matOff,
                                         const u16* __restrict__ g, int j0, int tid, bool neg)
{
    const int ch = tid & 7;
    const int r0 = tid >> 3;
    #pragma unroll
    for (int rr = 0; rr < 2; ++rr) {
        u32 dh = rr*32 + r0;
        us8 v = ((const us8*)(g + (size_t)dh*2048 + j0))[ch];
        if (neg) v = v ^ (u16)0x8000u;
        *(us8*)(Lp + matOff + dh*128u + (((u32)ch<<4) ^ ((dh&7u)<<4))) = v;
    }
}
__device__ __forceinline__ s8v ldfrag(const unsigned char* Lp, u32 matOff, u32 row, u32 colb)
{
    return *(const s8v*)(Lp + matOff + row*128u + (colb ^ ((row&7u)<<4)));
}

// ============================================================
// MFMA attention. Block = 256 thr (4 waves, 2x2 quadrants of 64x64).
// grid (bh=16, itile=32) -> blockid ≡ bh (mod 8): per-XCD L2 affinity.
// sweep1: hi*hi QK only -> approx row max m (cancels exactly in e/l).
// sweep2: 3-term split QK -> e=exp(s-m) -> attnbuf (unnorm), P=ac/as bf16
//         in LDS, PV via MFMA; epilogue folds 1/l into O, stores l.
// ============================================================
__global__ __launch_bounds__(256, 2)
void attn_mfma_kernel(const u16* __restrict__ qk,   // 8 mats
                      const u16* __restrict__ vt,   // 2 mats (transposed)
                      float* __restrict__ attnbuf,
                      float* __restrict__ o_r, float* __restrict__ o_i,
                      float* __restrict__ l_out)
{
    const int bh = blockIdx.x;
    const int i0 = blockIdx.y * 64;
    const int tid  = threadIdx.x;
    const int lane = tid & 63;
    const int wid  = tid >> 6;
    const int wr   = wid >> 1, wc = wid & 1;
    const int l31  = lane & 31;
    const int hi   = lane >> 5;
    const u32 rowA = wr*32 + l31;     // Q/P fragment row (local i)
    const u32 rowB = wc*32 + l31;     // K row (local j) / VT row (dh)

    __shared__ __align__(16) unsigned char L[81920];
    enum : u32 { QRH=0, QRL=8192, QIH=16384, QIL=24576,
                 KRH=32768, KRL=40960, KIH=49152, KIL=57344,
                 VRo=32768, VIo=40960, VNo=49152,
                 PAC=65536, PAS=73728 };

    const u16* qrh = qk + 0*MATE + (size_t)bh*BHE;
    const u16* qrl = qk + 1*MATE + (size_t)bh*BHE;
    const u16* qih = qk + 2*MATE + (size_t)bh*BHE;
    const u16* qil = qk + 3*MATE + (size_t)bh*BHE;
    const u16* krh = qk + 4*MATE + (size_t)bh*BHE;
    const u16* krl = qk + 5*MATE + (size_t)bh*BHE;
    const u16* kih = qk + 6*MATE + (size_t)bh*BHE;
    const u16* kil = qk + 7*MATE + (size_t)bh*BHE;
    const u16* vtr = vt + 0*MATE + (size_t)bh*BHE;
    const u16* vti = vt + 1*MATE + (size_t)bh*BHE;

    // stage Q (once)
    stage_qk(L, QRH, qrh, i0, tid);
    stage_qk(L, QRL, qrl, i0, tid);
    stage_qk(L, QIH, qih, i0, tid);
    stage_qk(L, QIL, qil, i0, tid);

    // ---------------- sweep 1: approx row max (hi*hi only) ----------------
    float mxv[16];
    #pragma unroll
    for (int r = 0; r < 16; ++r) mxv[r] = 0.f;

    for (int jt = 0; jt < 32; ++jt) {
        __syncthreads();
        stage_qk(L, KRH, krh, jt*64, tid);
        stage_qk(L, KIH, kih, jt*64, tid);
        __syncthreads();
        f32x16 ir, ip, in_;
        #pragma unroll
        for (int r = 0; r < 16; ++r) { ir[r]=0.f; ip[r]=0.f; in_[r]=0.f; }
        #pragma unroll
        for (int ks = 0; ks < 4; ++ks) {
            u32 colb = ks*32 + hi*16;
            s8v aR = ldfrag(L, QRH, rowA, colb);
            s8v aI = ldfrag(L, QIH, rowA, colb);
            s8v bR = ldfrag(L, KRH, rowB, colb);
            s8v bI = ldfrag(L, KIH, rowB, colb);
            ir  = MFMA32(aR, bR, ir);
            ir  = MFMA32(aI, bI, ir);
            ip  = MFMA32(aR, bI, ip);
            in_ = MFMA32(aI, bR, in_);
        }
        #pragma unroll
        for (int r = 0; r < 16; ++r) {
            float xr = ir[r], xi = ip[r] - in_[r];
            float q = xr*xr + xi*xi;
            mxv[r] = fmaxf(mxv[r], q * 0.125f);
        }
    }
    #pragma unroll
    for (int m = 1; m < 32; m <<= 1)
        #pragma unroll
        for (int r = 0; r < 16; ++r) mxv[r] = fmaxf(mxv[r], __shfl_xor(mxv[r], m));

    // cross-wave (wc) combine via scratch in P region
    float* sc = (float*)(L + PAC);
    __syncthreads();
    #pragma unroll
    for (int r = 0; r < 16; ++r)
        if (l31 == r) sc[wc*64 + wr*32 + ROWOF(r,hi)] = mxv[r];
    __syncthreads();
    float mfin[16];
    #pragma unroll
    for (int r = 0; r < 16; ++r) {
        u32 row = wr*32 + ROWOF(r,hi);
        mfin[r] = fmaxf(sc[row], sc[64 + row]);
    }

    // ---------------- sweep 2 ----------------
    f32x16 ore, oim;
    float lp[16];
    #pragma unroll
    for (int r = 0; r < 16; ++r) { ore[r]=0.f; oim[r]=0.f; lp[r]=0.f; }

    for (int jt = 0; jt < 32; ++jt) {
        const int j0 = jt * 64;
        __syncthreads();                       // prev PV done; K/V/P free
        stage_qk(L, KRH, krh, j0, tid);
        stage_qk(L, KRL, krl, j0, tid);
        stage_qk(L, KIH, kih, j0, tid);
        stage_qk(L, KIL, kil, j0, tid);
        __syncthreads();

        f32x16 ir, ip, in_;
        #pragma unroll
        for (int r = 0; r < 16; ++r) { ir[r]=0.f; ip[r]=0.f; in_[r]=0.f; }
        #pragma unroll
        for (int ks = 0; ks < 4; ++ks) {
            u32 colb = ks*32 + hi*16;
            s8v aRH = ldfrag(L, QRH, rowA, colb);
            s8v aRL = ldfrag(L, QRL, rowA, colb);
            s8v aIH = ldfrag(L, QIH, rowA, colb);
            s8v aIL = ldfrag(L, QIL, rowA, colb);
            s8v bRH = ldfrag(L, KRH, rowB, colb);
            s8v bRL = ldfrag(L, KRL, rowB, colb);
            s8v bIH = ldfrag(L, KIH, rowB, colb);
            s8v bIL = ldfrag(L, KIL, rowB, colb);
            // ir += Qr.Kr + Qi.Ki (3-term split each)
            ir = MFMA32(aRH, bRH, ir); ir = MFMA32(aRH, bRL, ir); ir = MFMA32(aRL, bRH, ir);
            ir = MFMA32(aIH, bIH, ir); ir = MFMA32(aIH, bIL, ir); ir = MFMA32(aIL, bIH, ir);
            // ip += Qr.Ki ; in_ += Qi.Kr   (ii = ip - in_)
            ip  = MFMA32(aRH, bIH, ip);  ip  = MFMA32(aRH, bIL, ip);  ip  = MFMA32(aRL, bIH, ip);
            in_ = MFMA32(aIH, bRH, in_); in_ = MFMA32(aIH, bRL, in_); in_ = MFMA32(aIL, bRH, in_);
        }
        __syncthreads();                       // K reads done -> stage V over K
        stage_vt(L, VRo, vtr, j0, tid, false);
        stage_vt(L, VIo, vti, j0, tid, false);
        stage_vt(L, VNo, vti, j0, tid, true);  // -Vi

        // pointwise: e, cos, sin; write attnbuf + P LDS
        float* arow = attnbuf + (size_t)bh*4194304ull + (size_t)i0*2048 + j0 + wc*32 + l31;
        #pragma unroll
        for (int r = 0; r < 16; ++r) {
            float xr = ir[r], xi = ip[r] - in_[r];
            float q  = fmaf(xr, xr, xi*xi);
            float e  = __expf(fmaf(q, 0.125f, -mfin[r]));
            lp[r] += e;
            float iv = rsqrtf(q);
            float cc = (q > 0.f) ? xr*iv : 1.0f;
            float ss = (q > 0.f) ? xi*iv : 0.0f;
            u32 rowloc = wr*32 + ROWOF(r,hi);
            arow[(size_t)rowloc*2048] = e;
            u32 colb2 = (wc*32 + l31)*2;
            *(u16*)(L + PAC + rowloc*128u + (colb2 ^ ((rowloc&7u)<<4))) = f2bf(e*cc);
            *(u16*)(L + PAS + rowloc*128u + (colb2 ^ ((rowloc&7u)<<4))) = f2bf(e*ss);
        }
        __syncthreads();                       // V + P visible

        #pragma unroll
        for (int ks = 0; ks < 4; ++ks) {
            u32 colb = ks*32 + hi*16;
            s8v aC = ldfrag(L, PAC, rowA, colb);
            s8v aS = ldfrag(L, PAS, rowA, colb);
            s8v vR = ldfrag(L, VRo, rowB, colb);
            s8v vI = ldfrag(L, VIo, rowB, colb);
            s8v vN = ldfrag(L, VNo, rowB, colb);
            ore = MFMA32(aC, vR, ore); ore = MFMA32(aS, vN, ore);
            oim = MFMA32(aS, vR, oim); oim = MFMA32(aC, vI, oim);
        }
    }

    // ---------------- epilogue: l, normalize, store ----------------
    #pragma unroll
    for (int m = 1; m < 32; m <<= 1)
        #pragma unroll
        for (int r = 0; r < 16; ++r) lp[r] += __shfl_xor(lp[r], m);

    __syncthreads();                           // last PV done -> reuse PAC scratch
    #pragma unroll
    for (int r = 0; r < 16; ++r)
        if (l31 == r) sc[wc*64 + wr*32 + ROWOF(r,hi)] = lp[r];
    __syncthreads();

    const int b_ = bh >> 3, h = bh & 7;
    float* orp = o_r + ((size_t)b_*2048 + i0)*512 + h*64 + wc*32 + l31;
    float* oip = o_i + ((size_t)b_*2048 + i0)*512 + h*64 + wc*32 + l31;
    #pragma unroll
    for (int r = 0; r < 16; ++r) {
        u32 row = wr*32 + ROWOF(r,hi);
        float ls = sc[row] + sc[64 + row];
        if (wc == 0 && l31 == 0) l_out[(size_t)bh*2048 + i0 + row] = ls;
        float inv = 1.0f / ls;
        orp[(size_t)row*512] = ore[r] * inv;
        oip[(size_t)row*512] = oim[r] * inv;
    }
}

// ============================================================
// attention *= 1/l[row]
// ============================================================
__global__ __launch_bounds__(256)
void scale_attn_kernel(float* __restrict__ attnbuf, const float* __restrict__ l)
{
    const size_t idx = (size_t)blockIdx.x * 256 + threadIdx.x;  // float4 index
    const size_t row = idx >> 9;
    const float inv = 1.f / l[row];
    float4* p = (float4*)attnbuf + idx;
    float4 v = *p;
    v.x *= inv; v.y *= inv; v.z *= inv; v.w *= inv;
    *p = v;
}

// ============================================================
// output projection: out = X @ Wo^T + bo
// ============================================================
__global__ __launch_bounds__(256)
void out_proj_kernel(const float* __restrict__ o_r, const float* __restrict__ o_i,
                     const float* __restrict__ Wo, const float* __restrict__ bo,
                     float* __restrict__ out)
{
    const int z = blockIdx.z;
    const float* X = z ? o_i : o_r;
    float* outp = out + (size_t)z * PE_;

    const int m0 = blockIdx.x * 64;
    const int n0 = blockIdx.y * 64;

    __shared__ float Xs[16][65];
    __shared__ float Wt[16][65];

    const int tid  = threadIdx.x;
    const int tx   = tid & 15, ty = tid >> 4;
    const int lrow = tid >> 2;
    const int kq   = (tid & 3) * 4;

    float acc[4][4] = {};

    for (int k0 = 0; k0 < 512; k0 += 16) {
        __syncthreads();
        float4 xv = *(const float4*)&X [(size_t)(m0 + lrow) * 512 + k0 + kq];
        float4 wv = *(const float4*)&Wo[(size_t)(n0 + lrow) * 512 + k0 + kq];
        Xs[kq+0][lrow] = xv.x; Xs[kq+1][lrow] = xv.y; Xs[kq+2][lrow] = xv.z; Xs[kq+3][lrow] = xv.w;
        Wt[kq+0][lrow] = wv.x; Wt[kq+1][lrow] = wv.y; Wt[kq+2][lrow] = wv.z; Wt[kq+3][lrow] = wv.w;
        __syncthreads();
        #pragma unroll
        for (int k = 0; k < 16; ++k) {
            float a[4], bb[4];
            #pragma unroll
            for (int r = 0; r < 4; ++r) a[r] = Xs[k][ty*4 + r];
            #pragma unroll
            for (int c = 0; c < 4; ++c) bb[c] = Wt[k][tx*4 + c];
            #pragma unroll
            for (int r = 0; r < 4; ++r)
                #pragma unroll
                for (int c = 0; c < 4; ++c) acc[r][c] += a[r] * bb[c];
        }
    }

    const float4 b4 = *(const float4*)&bo[n0 + tx*4];
    #pragma unroll
    for (int r = 0; r < 4; ++r) {
        const int t = m0 + ty*4 + r;
        float4 v;
        v.x = acc[r][0] + b4.x;
        v.y = acc[r][1] + b4.y;
        v.z = acc[r][2] + b4.z;
        v.w = acc[r][3] + b4.w;
        *(float4*)&outp[(size_t)t*512 + n0 + tx*4] = v;
    }
}

// ============================================================
extern "C" void kernel_launch(void* const* d_in, const int* in_sizes, int n_in,
                              void* d_out, int out_size, void* d_ws, size_t ws_size,
                              hipStream_t stream)
{
    const float* wave_real = (const float*)d_in[0];
    const float* wave_imag = (const float*)d_in[1];
    const float* Wq = (const float*)d_in[2]; const float* bq = (const float*)d_in[3];
    const float* Wk = (const float*)d_in[4]; const float* bk = (const float*)d_in[5];
    const float* Wv = (const float*)d_in[6]; const float* bv = (const float*)d_in[7];
    const float* Wo = (const float*)d_in[8]; const float* bo = (const float*)d_in[9];
    float* out = (float*)d_out;
    unsigned char* wsb = (unsigned char*)d_ws;

    float* attnbuf = out + 2*PE_;

    proj_qkv_kernel<<<dim3(64, 8, 6), dim3(256), 0, stream>>>(
        wave_real, wave_imag, Wq, bq, Wk, bk, Wv, bv, wsb);

    attn_mfma_kernel<<<dim3(16, 32), dim3(256), 0, stream>>>(
        (const u16*)wsb, (const u16*)(wsb + VT_OFF), attnbuf,
        (float*)(wsb + OR_OFF), (float*)(wsb + OI_OFF), (float*)(wsb + LV_OFF));

    scale_attn_kernel<<<dim3(65536), dim3(256), 0, stream>>>(
        attnbuf, (const float*)(wsb + LV_OFF));

    out_proj_kernel<<<dim3(64, 8, 2), dim3(256), 0, stream>>>(
        (const float*)(wsb + OR_OFF), (const float*)(wsb + OI_OFF), Wo, bo, out);
}

// Round 3
// 420.817 us; speedup vs baseline: 7.0298x; 1.5538x over previous
//
#include <hip/hip_runtime.h>

typedef unsigned short u16;
typedef unsigned int   u32;
typedef __attribute__((ext_vector_type(4)))  u16   us4;
typedef __attribute__((ext_vector_type(8)))  u16   us8;
typedef __attribute__((ext_vector_type(8)))  short s8v;
typedef __attribute__((ext_vector_type(16))) float f32x16;

#define L_   2048
#define D_   512
#define H_   8
#define PE_  2097152ull      // B*L*D elements of one fp32 projection array

// ---- ws layout (bytes) ----
//  [0 .. 32MB)   : 8 bf16 mats (QRH,QRL,QIH,QIL,KRH,KRL,KIH,KIL), each [bh][i][64]
//  [32 .. 40MB)  : 2 bf16 mats VTR,VTI, each [bh][dh][2048]  (V transposed)
//  [40 .. 56MB)  : o splits: ORH,ORL,OIH,OIL bf16 [4096][512]
//  [56MB ..]     : l (32768 fp32)
#define MATE    2097152ull   // u16 elems per mat
#define BHE     131072u      // u16 elems per (bh) slice of a mat (2048*64)
#define VT_OFF  33554432ull
#define ORH_OFF 41943040ull
#define ORL_OFF 46137344ull
#define OIH_OFF 50331648ull
#define OIL_OFF 54525952ull
#define LV_OFF  58720256ull

// ---- d_out scratch (bytes from out base; inside attnbuf, dead before attn writes) ----
#define XRH_O 16777216ull
#define XRL_O 20971520ull
#define XIH_O 25165824ull
#define XIL_O 29360128ull

#define MFMA32(a,b,c) __builtin_amdgcn_mfma_f32_32x32x16_bf16(a,b,c,0,0,0)
#define ROWOF(r,hi) (((r)&3) + 8*((r)>>2) + 4*(hi))

__device__ __forceinline__ u16 f2bf(float x){
    u32 u = __float_as_uint(x);
    u += 0x7FFFu + ((u>>16)&1u);
    return (u16)(u>>16);
}
__device__ __forceinline__ float bf2f(u16 h){ return __uint_as_float(((u32)h)<<16); }

// ============================================================
// Prep: split wave_real / wave_imag into bf16 hi/lo mats (d_out scratch)
// ============================================================
__global__ __launch_bounds__(256)
void split_prep_kernel(const float* __restrict__ wr, const float* __restrict__ wi,
                       unsigned char* __restrict__ outb)
{
    const int z = blockIdx.y;
    const float* src = z ? wi : wr;
    u16* hg = (u16*)(outb + (z ? XIH_O : XRH_O));
    u16* lg = (u16*)(outb + (z ? XIL_O : XRL_O));
    const size_t idx4 = ((size_t)blockIdx.x * 256 + threadIdx.x) * 4;
    float4 v = *(const float4*)&src[idx4];
    float vv[4] = { v.x, v.y, v.z, v.w };
    us4 h, l;
    #pragma unroll
    for (int c = 0; c < 4; ++c) {
        u16 hb = f2bf(vv[c]);
        h[c] = hb;
        l[c] = f2bf(vv[c] - bf2f(hb));
    }
    *(us4*)&hg[idx4] = h;
    *(us4*)&lg[idx4] = l;
}

// ============================================================
// Shared LDS fragment helpers (XOR swizzle byte ^= (row&7)<<4, both sides)
// ============================================================
__device__ __forceinline__ s8v ldfrag(const unsigned char* Lp, u32 matOff, u32 row, u32 colb)
{
    return *(const s8v*)(Lp + matOff + row*128u + (colb ^ ((row&7u)<<4)));
}

// ============================================================
// MFMA projection: C = X @ W^T + b for 6 combos.
// z: 0 Qr, 1 Qi, 2 Kr, 3 Ki (4-term split)  4 Vr, 5 Vi (plain bf16)
// A = X splits (bf16, d_out scratch), B = W fp32 split on-the-fly.
// Tile 128(M) x 64(N), K chunks of 64. 4 waves: (wr: M-half, wc: N-32-half).
// ============================================================
__global__ __launch_bounds__(256, 2)
void proj_mfma_kernel(const unsigned char* __restrict__ scr,
                      const float* __restrict__ Wq, const float* __restrict__ Wk,
                      const float* __restrict__ Wv,
                      const float* __restrict__ bq, const float* __restrict__ bk,
                      const float* __restrict__ bv,
                      u16* __restrict__ qk, u16* __restrict__ vt)
{
    const int z = blockIdx.z;
    const u16* Ah_g = (const u16*)(scr + ((z & 1) ? XIH_O : XRH_O));
    const u16* Al_g = (const u16*)(scr + ((z & 1) ? XIL_O : XRL_O));
    const int wsel = z >> 1;
    const float* Wf; const float* bias;
    if (wsel == 0)      { Wf = Wq; bias = bq; }
    else if (wsel == 1) { Wf = Wk; bias = bk; }
    else                { Wf = Wv; bias = bv; }
    const bool four = (wsel < 2);

    const int m0 = blockIdx.x * 128;
    const int n0 = blockIdx.y * 64;

    __shared__ __align__(16) unsigned char L[49152];
    enum : u32 { AH=0, AL=16384, BH=32768, BL=40960 };

    const int tid  = threadIdx.x;
    const int lane = tid & 63;
    const int wid  = tid >> 6;
    const int wr   = wid >> 1, wc = wid & 1;
    const int l31  = lane & 31;
    const int hi   = lane >> 5;
    const u32 rowA0 = (u32)(wr*64 + l31);
    const u32 rowB  = (u32)(wc*32 + l31);

    f32x16 c0, c1;
    #pragma unroll
    for (int r = 0; r < 16; ++r) { c0[r] = 0.f; c1[r] = 0.f; }

    const int ch = tid & 7, r0 = tid >> 3;

    for (int k0 = 0; k0 < 512; k0 += 64) {
        __syncthreads();
        // stage A (128 rows x 64 bf16), hi (+ lo if four)
        #pragma unroll
        for (int rr = 0; rr < 4; ++rr) {
            u32 row = (u32)(rr*32 + r0);
            u32 dst = row*128u + (((u32)ch<<4) ^ ((row&7u)<<4));
            us8 vh = *(const us8*)(Ah_g + (size_t)(m0 + row)*512 + k0 + ch*8);
            *(us8*)(L + AH + dst) = vh;
            if (four) {
                us8 vl = *(const us8*)(Al_g + (size_t)(m0 + row)*512 + k0 + ch*8);
                *(us8*)(L + AL + dst) = vl;
            }
        }
        // stage B (64 rows x 64) from fp32 W, split on the fly
        #pragma unroll
        for (int rr = 0; rr < 2; ++rr) {
            u32 row = (u32)(rr*32 + r0);
            const float* src = Wf + (size_t)(n0 + row)*512 + k0 + ch*8;
            float4 v0 = *(const float4*)src;
            float4 v1 = *(const float4*)(src + 4);
            float vv[8] = { v0.x,v0.y,v0.z,v0.w, v1.x,v1.y,v1.z,v1.w };
            us8 hv, lv;
            #pragma unroll
            for (int j = 0; j < 8; ++j) {
                u16 hb = f2bf(vv[j]);
                hv[j] = hb;
                lv[j] = f2bf(vv[j] - bf2f(hb));
            }
            u32 dst = row*128u + (((u32)ch<<4) ^ ((row&7u)<<4));
            *(us8*)(L + BH + dst) = hv;
            if (four) *(us8*)(L + BL + dst) = lv;
        }
        __syncthreads();

        #pragma unroll
        for (int ks = 0; ks < 4; ++ks) {
            u32 colb = (u32)(ks*32 + hi*16);
            s8v a0h = ldfrag(L, AH, rowA0,      colb);
            s8v a1h = ldfrag(L, AH, rowA0 + 32, colb);
            s8v bh_ = ldfrag(L, BH, rowB,       colb);
            c0 = MFMA32(a0h, bh_, c0);
            c1 = MFMA32(a1h, bh_, c1);
            if (four) {
                s8v a0l = ldfrag(L, AL, rowA0,      colb);
                s8v a1l = ldfrag(L, AL, rowA0 + 32, colb);
                s8v bl_ = ldfrag(L, BL, rowB,       colb);
                c0 = MFMA32(a0h, bl_, c0); c0 = MFMA32(a0l, bh_, c0); c0 = MFMA32(a0l, bl_, c0);
                c1 = MFMA32(a1h, bl_, c1); c1 = MFMA32(a1l, bh_, c1); c1 = MFMA32(a1l, bl_, c1);
            }
        }
    }

    // epilogue
    const int n  = n0 + wc*32 + l31;
    const float bvv = bias[n];
    const int h  = n >> 6, dh = n & 63;

    if (z < 4) {
        u16* hg = qk + (size_t)(2*z)   * MATE;
        u16* lg = qk + (size_t)(2*z+1) * MATE;
        #pragma unroll
        for (int f = 0; f < 2; ++f) {
            const f32x16& c = f ? c1 : c0;
            #pragma unroll
            for (int r = 0; r < 16; ++r) {
                int m  = m0 + wr*64 + 32*f + ROWOF(r, hi);
                int b_ = m >> 11, i = m & 2047;
                size_t idx = (size_t)(b_*8 + h)*BHE + (size_t)i*64 + dh;
                float v = c[r] + bvv;
                u16 hb = f2bf(v);
                hg[idx] = hb;
                lg[idx] = f2bf(v - bf2f(hb));
            }
        }
    } else {
        u16* vg = vt + (size_t)(z & 1) * MATE;
        #pragma unroll
        for (int f = 0; f < 2; ++f) {
            const f32x16& c = f ? c1 : c0;
            #pragma unroll
            for (int g = 0; g < 4; ++g) {
                int mb = m0 + wr*64 + 32*f + 8*g + 4*hi;
                int b_ = mb >> 11, ib = mb & 2047;
                us4 pv;
                #pragma unroll
                for (int j = 0; j < 4; ++j) pv[j] = f2bf(c[4*g + j] + bvv);
                *(us4*)&vg[(size_t)(b_*8 + h)*BHE + (size_t)dh*2048 + ib] = pv;
            }
        }
    }
}

// ============================================================
// LDS staging helpers for attention (unchanged)
// ============================================================
__device__ __forceinline__ void stage_qk(unsigned char* Lp, u32 matOff,
                                         const u16* __restrict__ g, int rowBase, int tid)
{
    const int ch = tid & 7;
    const int r0 = tid >> 3;
    #pragma unroll
    for (int rr = 0; rr < 2; ++rr) {
        u32 row = rr*32 + r0;
        us8 v = ((const us8*)(g + (size_t)(rowBase + row)*64))[ch];
        *(us8*)(Lp + matOff + row*128u + (((u32)ch<<4) ^ ((row&7u)<<4))) = v;
    }
}
__device__ __forceinline__ void stage_vt(unsigned char* Lp, u32 matOff,
                                         const u16* __restrict__ g, int j0, int tid, bool neg)
{
    const int ch = tid & 7;
    const int r0 = tid >> 3;
    #pragma unroll
    for (int rr = 0; rr < 2; ++rr) {
        u32 dh = rr*32 + r0;
        us8 v = ((const us8*)(g + (size_t)dh*2048 + j0))[ch];
        if (neg) v = v ^ (u16)0x8000u;
        *(us8*)(Lp + matOff + dh*128u + (((u32)ch<<4) ^ ((dh&7u)<<4))) = v;
    }
}

// ============================================================
// MFMA attention (core unchanged from round 2; epilogue -> o hi/lo bf16)
// ============================================================
__global__ __launch_bounds__(256, 2)
void attn_mfma_kernel(const u16* __restrict__ qk,
                      const u16* __restrict__ vt,
                      float* __restrict__ attnbuf,
                      u16* __restrict__ orh, u16* __restrict__ orl,
                      u16* __restrict__ oih, u16* __restrict__ oil,
                      float* __restrict__ l_out)
{
    const int bh = blockIdx.x;
    const int i0 = blockIdx.y * 64;
    const int tid  = threadIdx.x;
    const int lane = tid & 63;
    const int wid  = tid >> 6;
    const int wr   = wid >> 1, wc = wid & 1;
    const int l31  = lane & 31;
    const int hi   = lane >> 5;
    const u32 rowA = wr*32 + l31;
    const u32 rowB = wc*32 + l31;

    __shared__ __align__(16) unsigned char L[81920];
    enum : u32 { QRH=0, QRL=8192, QIH=16384, QIL=24576,
                 KRH=32768, KRL=40960, KIH=49152, KIL=57344,
                 VRo=32768, VIo=40960, VNo=49152,
                 PAC=65536, PAS=73728 };

    const u16* qrh = qk + 0*MATE + (size_t)bh*BHE;
    const u16* qrl = qk + 1*MATE + (size_t)bh*BHE;
    const u16* qih = qk + 2*MATE + (size_t)bh*BHE;
    const u16* qil = qk + 3*MATE + (size_t)bh*BHE;
    const u16* krh = qk + 4*MATE + (size_t)bh*BHE;
    const u16* krl = qk + 5*MATE + (size_t)bh*BHE;
    const u16* kih = qk + 6*MATE + (size_t)bh*BHE;
    const u16* kil = qk + 7*MATE + (size_t)bh*BHE;
    const u16* vtr = vt + 0*MATE + (size_t)bh*BHE;
    const u16* vti = vt + 1*MATE + (size_t)bh*BHE;

    stage_qk(L, QRH, qrh, i0, tid);
    stage_qk(L, QRL, qrl, i0, tid);
    stage_qk(L, QIH, qih, i0, tid);
    stage_qk(L, QIL, qil, i0, tid);

    // ---------------- sweep 1: approx row max (hi*hi only) ----------------
    float mxv[16];
    #pragma unroll
    for (int r = 0; r < 16; ++r) mxv[r] = 0.f;

    for (int jt = 0; jt < 32; ++jt) {
        __syncthreads();
        stage_qk(L, KRH, krh, jt*64, tid);
        stage_qk(L, KIH, kih, jt*64, tid);
        __syncthreads();
        f32x16 ir, ip, in_;
        #pragma unroll
        for (int r = 0; r < 16; ++r) { ir[r]=0.f; ip[r]=0.f; in_[r]=0.f; }
        #pragma unroll
        for (int ks = 0; ks < 4; ++ks) {
            u32 colb = ks*32 + hi*16;
            s8v aR = ldfrag(L, QRH, rowA, colb);
            s8v aI = ldfrag(L, QIH, rowA, colb);
            s8v bR = ldfrag(L, KRH, rowB, colb);
            s8v bI = ldfrag(L, KIH, rowB, colb);
            ir  = MFMA32(aR, bR, ir);
            ir  = MFMA32(aI, bI, ir);
            ip  = MFMA32(aR, bI, ip);
            in_ = MFMA32(aI, bR, in_);
        }
        #pragma unroll
        for (int r = 0; r < 16; ++r) {
            float xr = ir[r], xi = ip[r] - in_[r];
            float q = xr*xr + xi*xi;
            mxv[r] = fmaxf(mxv[r], q * 0.125f);
        }
    }
    #pragma unroll
    for (int m = 1; m < 32; m <<= 1)
        #pragma unroll
        for (int r = 0; r < 16; ++r) mxv[r] = fmaxf(mxv[r], __shfl_xor(mxv[r], m));

    float* sc = (float*)(L + PAC);
    __syncthreads();
    #pragma unroll
    for (int r = 0; r < 16; ++r)
        if (l31 == r) sc[wc*64 + wr*32 + ROWOF(r,hi)] = mxv[r];
    __syncthreads();
    float mfin[16];
    #pragma unroll
    for (int r = 0; r < 16; ++r) {
        u32 row = wr*32 + ROWOF(r,hi);
        mfin[r] = fmaxf(sc[row], sc[64 + row]);
    }

    // ---------------- sweep 2 ----------------
    f32x16 ore, oim;
    float lp[16];
    #pragma unroll
    for (int r = 0; r < 16; ++r) { ore[r]=0.f; oim[r]=0.f; lp[r]=0.f; }

    for (int jt = 0; jt < 32; ++jt) {
        const int j0 = jt * 64;
        __syncthreads();
        stage_qk(L, KRH, krh, j0, tid);
        stage_qk(L, KRL, krl, j0, tid);
        stage_qk(L, KIH, kih, j0, tid);
        stage_qk(L, KIL, kil, j0, tid);
        __syncthreads();

        f32x16 ir, ip, in_;
        #pragma unroll
        for (int r = 0; r < 16; ++r) { ir[r]=0.f; ip[r]=0.f; in_[r]=0.f; }
        #pragma unroll
        for (int ks = 0; ks < 4; ++ks) {
            u32 colb = ks*32 + hi*16;
            s8v aRH = ldfrag(L, QRH, rowA, colb);
            s8v aRL = ldfrag(L, QRL, rowA, colb);
            s8v aIH = ldfrag(L, QIH, rowA, colb);
            s8v aIL = ldfrag(L, QIL, rowA, colb);
            s8v bRH = ldfrag(L, KRH, rowB, colb);
            s8v bRL = ldfrag(L, KRL, rowB, colb);
            s8v bIH = ldfrag(L, KIH, rowB, colb);
            s8v bIL = ldfrag(L, KIL, rowB, colb);
            ir = MFMA32(aRH, bRH, ir); ir = MFMA32(aRH, bRL, ir); ir = MFMA32(aRL, bRH, ir);
            ir = MFMA32(aIH, bIH, ir); ir = MFMA32(aIH, bIL, ir); ir = MFMA32(aIL, bIH, ir);
            ip  = MFMA32(aRH, bIH, ip);  ip  = MFMA32(aRH, bIL, ip);  ip  = MFMA32(aRL, bIH, ip);
            in_ = MFMA32(aIH, bRH, in_); in_ = MFMA32(aIH, bRL, in_); in_ = MFMA32(aIL, bRH, in_);
        }
        __syncthreads();
        stage_vt(L, VRo, vtr, j0, tid, false);
        stage_vt(L, VIo, vti, j0, tid, false);
        stage_vt(L, VNo, vti, j0, tid, true);

        float* arow = attnbuf + (size_t)bh*4194304ull + (size_t)i0*2048 + j0 + wc*32 + l31;
        #pragma unroll
        for (int r = 0; r < 16; ++r) {
            float xr = ir[r], xi = ip[r] - in_[r];
            float q  = fmaf(xr, xr, xi*xi);
            float e  = __expf(fmaf(q, 0.125f, -mfin[r]));
            lp[r] += e;
            float iv = rsqrtf(q);
            float cc = (q > 0.f) ? xr*iv : 1.0f;
            float ss = (q > 0.f) ? xi*iv : 0.0f;
            u32 rowloc = wr*32 + ROWOF(r,hi);
            arow[(size_t)rowloc*2048] = e;
            u32 colb2 = (wc*32 + l31)*2;
            *(u16*)(L + PAC + rowloc*128u + (colb2 ^ ((rowloc&7u)<<4))) = f2bf(e*cc);
            *(u16*)(L + PAS + rowloc*128u + (colb2 ^ ((rowloc&7u)<<4))) = f2bf(e*ss);
        }
        __syncthreads();

        #pragma unroll
        for (int ks = 0; ks < 4; ++ks) {
            u32 colb = ks*32 + hi*16;
            s8v aC = ldfrag(L, PAC, rowA, colb);
            s8v aS = ldfrag(L, PAS, rowA, colb);
            s8v vR = ldfrag(L, VRo, rowB, colb);
            s8v vI = ldfrag(L, VIo, rowB, colb);
            s8v vN = ldfrag(L, VNo, rowB, colb);
            ore = MFMA32(aC, vR, ore); ore = MFMA32(aS, vN, ore);
            oim = MFMA32(aS, vR, oim); oim = MFMA32(aC, vI, oim);
        }
    }

    // ---------------- epilogue ----------------
    #pragma unroll
    for (int m = 1; m < 32; m <<= 1)
        #pragma unroll
        for (int r = 0; r < 16; ++r) lp[r] += __shfl_xor(lp[r], m);

    __syncthreads();
    #pragma unroll
    for (int r = 0; r < 16; ++r)
        if (l31 == r) sc[wc*64 + wr*32 + ROWOF(r,hi)] = lp[r];
    __syncthreads();

    const int b_ = bh >> 3, h = bh & 7;
    const size_t cb = (size_t)h*64 + wc*32 + l31;
    #pragma unroll
    for (int r = 0; r < 16; ++r) {
        u32 row = wr*32 + ROWOF(r,hi);
        float ls = sc[row] + sc[64 + row];
        if (wc == 0 && l31 == 0) l_out[(size_t)bh*2048 + i0 + row] = ls;
        float inv = 1.0f / ls;
        size_t idx = ((size_t)b_*2048 + i0 + row)*512 + cb;
        float vr = ore[r] * inv;
        float vi = oim[r] * inv;
        u16 hr = f2bf(vr); orh[idx] = hr; orl[idx] = f2bf(vr - bf2f(hr));
        u16 hiw = f2bf(vi); oih[idx] = hiw; oil[idx] = f2bf(vi - bf2f(hiw));
    }
}

// ============================================================
// attention *= 1/l[row]
// ============================================================
__global__ __launch_bounds__(256)
void scale_attn_kernel(float* __restrict__ attnbuf, const float* __restrict__ l)
{
    const size_t idx = (size_t)blockIdx.x * 256 + threadIdx.x;
    const size_t row = idx >> 9;
    const float inv = 1.f / l[row];
    float4* p = (float4*)attnbuf + idx;
    float4 v = *p;
    v.x *= inv; v.y *= inv; v.z *= inv; v.w *= inv;
    *p = v;
}

// ============================================================
// O projection: out = o @ Wo^T + bo, 3-term split-bf16 MFMA.
// A = o splits (ws), B = Wo fp32 split on-the-fly. Tile 128x64.
// ============================================================
__global__ __launch_bounds__(256, 2)
void oproj_mfma_kernel(const unsigned char* __restrict__ wsb,
                       const float* __restrict__ Wo, const float* __restrict__ bo,
                       float* __restrict__ out)
{
    const int z = blockIdx.z;
    const u16* Ah_g = (const u16*)(wsb + (z ? OIH_OFF : ORH_OFF));
    const u16* Al_g = (const u16*)(wsb + (z ? OIL_OFF : ORL_OFF));
    float* outp = out + (size_t)z * PE_;

    const int m0 = blockIdx.x * 128;
    const int n0 = blockIdx.y * 64;

    __shared__ __align__(16) unsigned char L[49152];
    enum : u32 { AH=0, AL=16384, BH=32768, BL=40960 };

    const int tid  = threadIdx.x;
    const int lane = tid & 63;
    const int wid  = tid >> 6;
    const int wr   = wid >> 1, wc = wid & 1;
    const int l31  = lane & 31;
    const int hi   = lane >> 5;
    const u32 rowA0 = (u32)(wr*64 + l31);
    const u32 rowB  = (u32)(wc*32 + l31);

    f32x16 c0, c1;
    #pragma unroll
    for (int r = 0; r < 16; ++r) { c0[r] = 0.f; c1[r] = 0.f; }

    const int ch = tid & 7, r0 = tid >> 3;

    for (int k0 = 0; k0 < 512; k0 += 64) {
        __syncthreads();
        #pragma unroll
        for (int rr = 0; rr < 4; ++rr) {
            u32 row = (u32)(rr*32 + r0);
            u32 dst = row*128u + (((u32)ch<<4) ^ ((row&7u)<<4));
            us8 vh = *(const us8*)(Ah_g + (size_t)(m0 + row)*512 + k0 + ch*8);
            us8 vl = *(const us8*)(Al_g + (size_t)(m0 + row)*512 + k0 + ch*8);
            *(us8*)(L + AH + dst) = vh;
            *(us8*)(L + AL + dst) = vl;
        }
        #pragma unroll
        for (int rr = 0; rr < 2; ++rr) {
            u32 row = (u32)(rr*32 + r0);
            const float* src = Wo + (size_t)(n0 + row)*512 + k0 + ch*8;
            float4 v0 = *(const float4*)src;
            float4 v1 = *(const float4*)(src + 4);
            float vv[8] = { v0.x,v0.y,v0.z,v0.w, v1.x,v1.y,v1.z,v1.w };
            us8 hv, lv;
            #pragma unroll
            for (int j = 0; j < 8; ++j) {
                u16 hb = f2bf(vv[j]);
                hv[j] = hb;
                lv[j] = f2bf(vv[j] - bf2f(hb));
            }
            u32 dst = row*128u + (((u32)ch<<4) ^ ((row&7u)<<4));
            *(us8*)(L + BH + dst) = hv;
            *(us8*)(L + BL + dst) = lv;
        }
        __syncthreads();

        #pragma unroll
        for (int ks = 0; ks < 4; ++ks) {
            u32 colb = (u32)(ks*32 + hi*16);
            s8v a0h = ldfrag(L, AH, rowA0,      colb);
            s8v a1h = ldfrag(L, AH, rowA0 + 32, colb);
            s8v a0l = ldfrag(L, AL, rowA0,      colb);
            s8v a1l = ldfrag(L, AL, rowA0 + 32, colb);
            s8v bh_ = ldfrag(L, BH, rowB,       colb);
            s8v bl_ = ldfrag(L, BL, rowB,       colb);
            c0 = MFMA32(a0h, bh_, c0); c0 = MFMA32(a0h, bl_, c0); c0 = MFMA32(a0l, bh_, c0);
            c1 = MFMA32(a1h, bh_, c1); c1 = MFMA32(a1h, bl_, c1); c1 = MFMA32(a1l, bh_, c1);
        }
    }

    const int n = n0 + wc*32 + l31;
    const float bvv = bo[n];
    #pragma unroll
    for (int f = 0; f < 2; ++f) {
        const f32x16& c = f ? c1 : c0;
        #pragma unroll
        for (int r = 0; r < 16; ++r) {
            int m = m0 + wr*64 + 32*f + ROWOF(r, hi);
            outp[(size_t)m*512 + n] = c[r] + bvv;
        }
    }
}

// ============================================================
extern "C" void kernel_launch(void* const* d_in, const int* in_sizes, int n_in,
                              void* d_out, int out_size, void* d_ws, size_t ws_size,
                              hipStream_t stream)
{
    const float* wave_real = (const float*)d_in[0];
    const float* wave_imag = (const float*)d_in[1];
    const float* Wq = (const float*)d_in[2]; const float* bq = (const float*)d_in[3];
    const float* Wk = (const float*)d_in[4]; const float* bk = (const float*)d_in[5];
    const float* Wv = (const float*)d_in[6]; const float* bv = (const float*)d_in[7];
    const float* Wo = (const float*)d_in[8]; const float* bo = (const float*)d_in[9];
    float* out = (float*)d_out;
    unsigned char* outb = (unsigned char*)d_out;
    unsigned char* wsb  = (unsigned char*)d_ws;

    float* attnbuf = out + 2*PE_;

    split_prep_kernel<<<dim3(2048, 2), dim3(256), 0, stream>>>(wave_real, wave_imag, outb);

    proj_mfma_kernel<<<dim3(32, 8, 6), dim3(256), 0, stream>>>(
        outb, Wq, Wk, Wv, bq, bk, bv,
        (u16*)wsb, (u16*)(wsb + VT_OFF));

    attn_mfma_kernel<<<dim3(16, 32), dim3(256), 0, stream>>>(
        (const u16*)wsb, (const u16*)(wsb + VT_OFF), attnbuf,
        (u16*)(wsb + ORH_OFF), (u16*)(wsb + ORL_OFF),
        (u16*)(wsb + OIH_OFF), (u16*)(wsb + OIL_OFF),
        (float*)(wsb + LV_OFF));

    scale_attn_kernel<<<dim3(65536), dim3(256), 0, stream>>>(
        attnbuf, (const float*)(wsb + LV_OFF));

    oproj_mfma_kernel<<<dim3(32, 8, 2), dim3(256), 0, stream>>>(
        wsb, Wo, bo, out);
}